// Round 1
// baseline (299.324 us; speedup 1.0000x reference)
//
#include <hip/hip_runtime.h>
#include <hip/hip_bf16.h>
#include <cstdint>
#include <cstddef>

using bf16 = __hip_bfloat16;
typedef __attribute__((ext_vector_type(8))) short short8;
typedef __attribute__((ext_vector_type(4))) float f32x4;

#define MFMA16(a, b, c) __builtin_amdgcn_mfma_f32_16x16x32_bf16((a), (b), (c), 0, 0, 0)

static constexpr int S = 2048;
static constexpr int E = 2048;
static constexpr int H = 16;
static constexpr int KVH = 4;
static constexpr int Dh = 128;
static constexpr int NQKV = 3072;        // 2048 q + 512 k + 512 v
static constexpr float ATTN_SCALE = 0.08838834764831845f; // 1/sqrt(128)

__device__ __forceinline__ short f2bs(float f) {
  __hip_bfloat16 h = __float2bfloat16(f);
  return *reinterpret_cast<short*>(&h);
}

__device__ __forceinline__ void gload_lds16(const void* g, void* l) {
  __builtin_amdgcn_global_load_lds(
      (const __attribute__((address_space(1))) unsigned int*)g,
      (__attribute__((address_space(3))) unsigned int*)l,
      16, 0, 0);
}

// ---------------- f32 -> bf16 convert (vectorized, 8 elems/thread) -------------
__global__ void cvt_bf16(const float* __restrict__ src, bf16* __restrict__ dst, int n) {
  int i = (blockIdx.x * 256 + threadIdx.x) * 8;
  if (i + 8 > n) return;
  const float4* s4 = reinterpret_cast<const float4*>(src + i);
  float4 a = s4[0];
  float4 b = s4[1];
  short8 o;
  o[0] = f2bs(a.x); o[1] = f2bs(a.y); o[2] = f2bs(a.z); o[3] = f2bs(a.w);
  o[4] = f2bs(b.x); o[5] = f2bs(b.y); o[6] = f2bs(b.z); o[7] = f2bs(b.w);
  *reinterpret_cast<short8*>(dst + i) = o;
}

// ---------------- GEMM: C[m][n] = sum_k A[m][k] * B[n][k]  (both row-major) ----
// 128x128 tile, BK=32, 4 waves (2x2), each wave 64x64 via 4x4 16x16x32 MFMA frags.
template <bool OUT_F32>
__global__ __launch_bounds__(256, 2) void gemm_nt(const bf16* __restrict__ A,
                                                  const bf16* __restrict__ B,
                                                  void* __restrict__ Cout,
                                                  int M, int N, int K) {
  __shared__ bf16 As[128 * 32];
  __shared__ bf16 Bs[128 * 32];
  const int tid = threadIdx.x;
  const int lane = tid & 63;
  const int wv = tid >> 6;
  const int lr = lane & 15, lq = lane >> 4;
  const int wm = (wv >> 1) * 64, wn = (wv & 1) * 64;
  const int bm = blockIdx.x * 128, bn = blockIdx.y * 128;

  f32x4 acc[4][4] = {};

  for (int k0 = 0; k0 < K; k0 += 32) {
    __syncthreads();  // previous compute done before overwrite
    for (int it = 0; it < 2; ++it) {
      int ci = it * 256 + tid;          // chunk index, 16B chunks; 4 chunks/row
      int row = ci >> 2, co = (ci & 3) * 8;
      gload_lds16(A + (size_t)(bm + row) * K + k0 + co, As + (it * 256 + wv * 64) * 8);
      gload_lds16(B + (size_t)(bn + row) * K + k0 + co, Bs + (it * 256 + wv * 64) * 8);
    }
    __syncthreads();  // compiler drains vmcnt before barrier

    short8 af[4], bfr[4];
#pragma unroll
    for (int im = 0; im < 4; ++im)
      af[im] = *reinterpret_cast<const short8*>(As + (wm + im * 16 + lr) * 32 + lq * 8);
#pragma unroll
    for (int jn = 0; jn < 4; ++jn)
      bfr[jn] = *reinterpret_cast<const short8*>(Bs + (wn + jn * 16 + lr) * 32 + lq * 8);
#pragma unroll
    for (int im = 0; im < 4; ++im)
#pragma unroll
      for (int jn = 0; jn < 4; ++jn)
        acc[im][jn] = MFMA16(af[im], bfr[jn], acc[im][jn]);
  }

#pragma unroll
  for (int im = 0; im < 4; ++im)
#pragma unroll
    for (int jn = 0; jn < 4; ++jn)
#pragma unroll
      for (int i = 0; i < 4; ++i) {
        int r = bm + wm + im * 16 + lq * 4 + i;
        int c = bn + wn + jn * 16 + lr;
        if (OUT_F32)
          reinterpret_cast<float*>(Cout)[(size_t)r * N + c] = acc[im][jn][i];
        else
          reinterpret_cast<bf16*>(Cout)[(size_t)r * N + c] = __float2bfloat16(acc[im][jn][i]);
      }
}

// ---------------- QK RMSNorm + RoPE -------------------------------------------
// one wave per (s, head) row; heads 0..15 = Q, 16..19 = K(kv)
__global__ void qk_norm_rope(const bf16* __restrict__ QKV,
                             const float* __restrict__ qw, const float* __restrict__ kw,
                             bf16* __restrict__ Qn, bf16* __restrict__ Kn) {
  const int lane = threadIdx.x & 63;
  const int w = threadIdx.x >> 6;
  const int row = blockIdx.x * 4 + w;   // 0 .. 2048*20-1
  const int s = row / 20;
  const int hh = row % 20;

  const bf16* src;
  bf16* dst;
  const float* wt;
  if (hh < 16) {
    src = QKV + (size_t)s * NQKV + hh * Dh;
    dst = Qn + ((size_t)hh * S + s) * Dh;
    wt = qw;
  } else {
    int kvh = hh - 16;
    src = QKV + (size_t)s * NQKV + 2048 + kvh * Dh;
    dst = Kn + ((size_t)kvh * S + s) * Dh;
    wt = kw;
  }

  float x0 = __bfloat162float(src[lane]);
  float x1 = __bfloat162float(src[lane + 64]);
  float ss = x0 * x0 + x1 * x1;
#pragma unroll
  for (int off = 1; off < 64; off <<= 1) ss += __shfl_xor(ss, off);
  float rms = rsqrtf(ss * (1.0f / 128.0f) + 1e-6f);
  float n0 = x0 * rms * wt[lane];
  float n1 = x1 * rms * wt[lane + 64];

  // inv_freq = 10000^(-lane/64) = exp2(-lane * log2(10000)/64)
  float inv_freq = exp2f((float)lane * -0.2076205059304601f);
  float ang = (float)s * inv_freq;
  float sn, cs;
  sincosf(ang, &sn, &cs);
  float o0 = n0 * cs - n1 * sn;
  float o1 = n1 * cs + n0 * sn;
  dst[lane] = __float2bfloat16(o0);
  dst[lane + 64] = __float2bfloat16(o1);
}

// ---------------- V transpose: Vt[kvh][d][s] = QKV[s][2560 + kvh*128 + d] ------
__global__ void v_transpose(const bf16* __restrict__ QKV, bf16* __restrict__ Vt) {
  __shared__ bf16 t[64][65];
  const int s0 = blockIdx.x * 64;
  const int c0 = blockIdx.y * 64;           // within 512 v-cols
  const int kvh = c0 >> 7, d0 = c0 & 127;
#pragma unroll 4
  for (int i = 0; i < 16; ++i) {
    int lin = i * 256 + threadIdx.x;
    int r = lin >> 6, c = lin & 63;
    t[r][c] = QKV[(size_t)(s0 + r) * NQKV + 2560 + c0 + c];
  }
  __syncthreads();
#pragma unroll 4
  for (int i = 0; i < 16; ++i) {
    int lin = i * 256 + threadIdx.x;
    int d = lin >> 6, s = lin & 63;
    Vt[((size_t)kvh * 128 + d0 + d) * S + s0 + s] = t[s][d];
  }
}

// ---------------- causal GQA flash attention ----------------------------------
// grid (S/128, H); 4 waves/block, each wave owns 32 q-rows independently.
__global__ __launch_bounds__(256, 1) void attn_fwd(const bf16* __restrict__ Qn,
                                                   const bf16* __restrict__ Kn,
                                                   const bf16* __restrict__ Vt,
                                                   bf16* __restrict__ AO) {
  __shared__ bf16 Plds[4][32 * 136];   // +8 pad per row, per-wave private
  const int tid = threadIdx.x;
  const int lane = tid & 63;
  const int w = tid >> 6;
  const int lr = lane & 15, lq = lane >> 4;
  const int h = blockIdx.y, kvh = h >> 2;
  const int sq = blockIdx.x * 128 + w * 32;

  const bf16* Qbase = Qn + ((size_t)h * S + sq) * Dh;
  const bf16* Kbase = Kn + (size_t)kvh * S * Dh;
  const bf16* Vbase = Vt + (size_t)kvh * Dh * S;
  bf16* Pw = &Plds[w][0];

  short8 qf[2][4];
#pragma unroll
  for (int im = 0; im < 2; ++im)
#pragma unroll
    for (int dd = 0; dd < 4; ++dd)
      qf[im][dd] = *reinterpret_cast<const short8*>(Qbase + (size_t)(im * 16 + lr) * Dh + dd * 32 + lq * 8);

  float mrow[2][4], lrow[2][4];
  f32x4 oacc[2][8] = {};
#pragma unroll
  for (int im = 0; im < 2; ++im)
#pragma unroll
    for (int i = 0; i < 4; ++i) { mrow[im][i] = -INFINITY; lrow[im][i] = 0.0f; }

  const int ntiles = (sq + 31) / 128 + 1;
  for (int kt = 0; kt < ntiles; ++kt) {
    const int kb = kt * 128;
    f32x4 sacc[2][8] = {};
#pragma unroll
    for (int jn = 0; jn < 8; ++jn) {
      const bf16* kp = Kbase + (size_t)(kb + jn * 16 + lr) * Dh + lq * 8;
#pragma unroll
      for (int dd = 0; dd < 4; ++dd) {
        short8 bfr = *reinterpret_cast<const short8*>(kp + dd * 32);
        sacc[0][jn] = MFMA16(qf[0][dd], bfr, sacc[0][jn]);
        sacc[1][jn] = MFMA16(qf[1][dd], bfr, sacc[1][jn]);
      }
    }
    const bool last = (kt == ntiles - 1);

#pragma unroll
    for (int im = 0; im < 2; ++im) {
      float pm[4] = {-INFINITY, -INFINITY, -INFINITY, -INFINITY};
#pragma unroll
      for (int jn = 0; jn < 8; ++jn)
#pragma unroll
        for (int i = 0; i < 4; ++i) {
          float v = sacc[im][jn][i] * ATTN_SCALE;
          if (last) {
            int kg = kb + jn * 16 + lr;
            int qg = sq + im * 16 + lq * 4 + i;
            if (kg > qg) v = -INFINITY;
          }
          sacc[im][jn][i] = v;
          pm[i] = fmaxf(pm[i], v);
        }
#pragma unroll
      for (int i = 0; i < 4; ++i) {
#pragma unroll
        for (int off = 1; off < 16; off <<= 1) pm[i] = fmaxf(pm[i], __shfl_xor(pm[i], off));
      }
      float alpha[4], rs[4];
#pragma unroll
      for (int i = 0; i < 4; ++i) {
        float mnew = fmaxf(mrow[im][i], pm[i]);
        alpha[i] = __expf(mrow[im][i] - mnew);
        mrow[im][i] = mnew;
        rs[i] = 0.0f;
      }
#pragma unroll
      for (int jn = 0; jn < 8; ++jn)
#pragma unroll
        for (int i = 0; i < 4; ++i) {
          float p = __expf(sacc[im][jn][i] - mrow[im][i]);
          sacc[im][jn][i] = p;
          rs[i] += p;
        }
#pragma unroll
      for (int i = 0; i < 4; ++i) {
#pragma unroll
        for (int off = 1; off < 16; off <<= 1) rs[i] += __shfl_xor(rs[i], off);
        lrow[im][i] = lrow[im][i] * alpha[i] + rs[i];
      }
#pragma unroll
      for (int jd = 0; jd < 8; ++jd)
#pragma unroll
        for (int i = 0; i < 4; ++i) oacc[im][jd][i] *= alpha[i];
      // P -> LDS (row-major [32][136])
#pragma unroll
      for (int jn = 0; jn < 8; ++jn)
#pragma unroll
        for (int i = 0; i < 4; ++i)
          Pw[(im * 16 + lq * 4 + i) * 136 + jn * 16 + lr] = __float2bfloat16(sacc[im][jn][i]);
    }
    __builtin_amdgcn_wave_barrier();

    // O += P @ V
#pragma unroll
    for (int kk = 0; kk < 4; ++kk) {
      short8 pa0 = *reinterpret_cast<const short8*>(Pw + (0 + lr) * 136 + kk * 32 + lq * 8);
      short8 pa1 = *reinterpret_cast<const short8*>(Pw + (16 + lr) * 136 + kk * 32 + lq * 8);
#pragma unroll
      for (int jd = 0; jd < 8; ++jd) {
        short8 vf = *reinterpret_cast<const short8*>(Vbase + (size_t)(jd * 16 + lr) * S + kb + kk * 32 + lq * 8);
        oacc[0][jd] = MFMA16(pa0, vf, oacc[0][jd]);
        oacc[1][jd] = MFMA16(pa1, vf, oacc[1][jd]);
      }
    }
    __builtin_amdgcn_wave_barrier();
  }

#pragma unroll
  for (int im = 0; im < 2; ++im)
#pragma unroll
    for (int jd = 0; jd < 8; ++jd)
#pragma unroll
      for (int i = 0; i < 4; ++i) {
        float o = oacc[im][jd][i] / lrow[im][i];
        AO[(size_t)(sq + im * 16 + lq * 4 + i) * E + h * Dh + jd * 16 + lr] = __float2bfloat16(o);
      }
}

// ------------------------------------------------------------------------------
extern "C" void kernel_launch(void* const* d_in, const int* in_sizes, int n_in,
                              void* d_out, int out_size, void* d_ws, size_t ws_size,
                              hipStream_t stream) {
  const float* x  = (const float*)d_in[0];
  // d_in[1] = mask (causal triu k=1) — hardcoded in attn kernel
  const float* Wq = (const float*)d_in[2];
  const float* Wk = (const float*)d_in[3];
  const float* Wv = (const float*)d_in[4];
  const float* Wo = (const float*)d_in[5];
  const float* qw = (const float*)d_in[6];
  const float* kw = (const float*)d_in[7];

  char* ws = (char*)d_ws;
  bf16* xb   = (bf16*)(ws + (0ull << 20));    // [2048][2048]   8 MB
  bf16* Wcat = (bf16*)(ws + (8ull << 20));    // [3072][2048]  12 MB
  bf16* Wob  = (bf16*)(ws + (20ull << 20));   // [2048][2048]   8 MB
  bf16* QKV  = (bf16*)(ws + (28ull << 20));   // [2048][3072]  12 MB
  bf16* Qn   = (bf16*)(ws + (40ull << 20));   // [16][2048][128] 8 MB
  bf16* Kn   = (bf16*)(ws + (48ull << 20));   // [4][2048][128]  2 MB
  bf16* Vt   = (bf16*)(ws + (50ull << 20));   // [4][128][2048]  2 MB
  bf16* AO   = (bf16*)(ws + (52ull << 20));   // [2048][2048]    8 MB

  cvt_bf16<<<2048, 256, 0, stream>>>(x, xb, E * S);
  cvt_bf16<<<2048, 256, 0, stream>>>(Wq, Wcat, E * E);
  cvt_bf16<<<512, 256, 0, stream>>>(Wk, Wcat + 2048 * 2048, 512 * E);
  cvt_bf16<<<512, 256, 0, stream>>>(Wv, Wcat + 2560 * 2048, 512 * E);
  cvt_bf16<<<2048, 256, 0, stream>>>(Wo, Wob, E * E);

  gemm_nt<false><<<dim3(S / 128, NQKV / 128), 256, 0, stream>>>(xb, Wcat, QKV, S, NQKV, E);

  qk_norm_rope<<<(S * 20) / 4, 256, 0, stream>>>(QKV, qw, kw, Qn, Kn);
  v_transpose<<<dim3(S / 64, 512 / 64), 256, 0, stream>>>(QKV, Vt);

  attn_fwd<<<dim3(S / 128, H), 256, 0, stream>>>(Qn, Kn, Vt, AO);

  gemm_nt<true><<<dim3(S / 128, E / 128), 256, 0, stream>>>(AO, Wob, d_out, S, E, E);
}

// Round 2
// 232.402 us; speedup vs baseline: 1.2880x; 1.2880x over previous
//
#include <hip/hip_runtime.h>
#include <hip/hip_bf16.h>
#include <cstdint>
#include <cstddef>

using bf16 = __hip_bfloat16;
typedef __attribute__((ext_vector_type(8))) short short8;
typedef __attribute__((ext_vector_type(4))) float f32x4;

#define MFMA16(a, b, c) __builtin_amdgcn_mfma_f32_16x16x32_bf16((a), (b), (c), 0, 0, 0)

static constexpr int S = 2048;
static constexpr int E = 2048;
static constexpr int H = 16;
static constexpr int KVH = 4;
static constexpr int Dh = 128;
static constexpr int NQKV = 3072;        // 2048 q + 512 k + 512 v
static constexpr float ATTN_SCALE = 0.08838834764831845f; // 1/sqrt(128)

__device__ __forceinline__ short f2bs(float f) {
  __hip_bfloat16 h = __float2bfloat16(f);
  return *reinterpret_cast<short*>(&h);
}

__device__ __forceinline__ void gload_lds16(const void* g, void* l) {
  __builtin_amdgcn_global_load_lds(
      (const __attribute__((address_space(1))) unsigned int*)g,
      (__attribute__((address_space(3))) unsigned int*)l,
      16, 0, 0);
}

// ---------------- f32 -> bf16 convert (vectorized, 8 elems/thread) -------------
__global__ void cvt_bf16(const float* __restrict__ src, bf16* __restrict__ dst, int n) {
  int i = (blockIdx.x * 256 + threadIdx.x) * 8;
  if (i + 8 > n) return;
  const float4* s4 = reinterpret_cast<const float4*>(src + i);
  float4 a = s4[0];
  float4 b = s4[1];
  short8 o;
  o[0] = f2bs(a.x); o[1] = f2bs(a.y); o[2] = f2bs(a.z); o[3] = f2bs(a.w);
  o[4] = f2bs(b.x); o[5] = f2bs(b.y); o[6] = f2bs(b.z); o[7] = f2bs(b.w);
  *reinterpret_cast<short8*>(dst + i) = o;
}

// ---------------- GEMM: C[m][n] = sum_k A[m][k] * B[n][k]  (both row-major) ----
template <bool OUT_F32>
__global__ __launch_bounds__(256, 2) void gemm_nt(const bf16* __restrict__ A,
                                                  const bf16* __restrict__ B,
                                                  void* __restrict__ Cout,
                                                  int M, int N, int K) {
  __shared__ bf16 As[128 * 32];
  __shared__ bf16 Bs[128 * 32];
  const int tid = threadIdx.x;
  const int lane = tid & 63;
  const int wv = tid >> 6;
  const int lr = lane & 15, lq = lane >> 4;
  const int wm = (wv >> 1) * 64, wn = (wv & 1) * 64;
  const int bm = blockIdx.x * 128, bn = blockIdx.y * 128;

  f32x4 acc[4][4] = {};

  for (int k0 = 0; k0 < K; k0 += 32) {
    __syncthreads();
    for (int it = 0; it < 2; ++it) {
      int ci = it * 256 + tid;
      int row = ci >> 2, co = (ci & 3) * 8;
      gload_lds16(A + (size_t)(bm + row) * K + k0 + co, As + (it * 256 + wv * 64) * 8);
      gload_lds16(B + (size_t)(bn + row) * K + k0 + co, Bs + (it * 256 + wv * 64) * 8);
    }
    __syncthreads();

    short8 af[4], bfr[4];
#pragma unroll
    for (int im = 0; im < 4; ++im)
      af[im] = *reinterpret_cast<const short8*>(As + (wm + im * 16 + lr) * 32 + lq * 8);
#pragma unroll
    for (int jn = 0; jn < 4; ++jn)
      bfr[jn] = *reinterpret_cast<const short8*>(Bs + (wn + jn * 16 + lr) * 32 + lq * 8);
#pragma unroll
    for (int im = 0; im < 4; ++im)
#pragma unroll
      for (int jn = 0; jn < 4; ++jn)
        acc[im][jn] = MFMA16(af[im], bfr[jn], acc[im][jn]);
  }

#pragma unroll
  for (int im = 0; im < 4; ++im)
#pragma unroll
    for (int jn = 0; jn < 4; ++jn)
#pragma unroll
      for (int i = 0; i < 4; ++i) {
        int r = bm + wm + im * 16 + lq * 4 + i;
        int c = bn + wn + jn * 16 + lr;
        if (OUT_F32)
          reinterpret_cast<float*>(Cout)[(size_t)r * N + c] = acc[im][jn][i];
        else
          reinterpret_cast<bf16*>(Cout)[(size_t)r * N + c] = __float2bfloat16(acc[im][jn][i]);
      }
}

// ---------------- QK RMSNorm + RoPE (Q pre-scaled by 1/sqrt(Dh)) ---------------
__global__ void qk_norm_rope(const bf16* __restrict__ QKV,
                             const float* __restrict__ qw, const float* __restrict__ kw,
                             bf16* __restrict__ Qn, bf16* __restrict__ Kn) {
  const int lane = threadIdx.x & 63;
  const int w = threadIdx.x >> 6;
  const int row = blockIdx.x * 4 + w;
  const int s = row / 20;
  const int hh = row % 20;

  const bf16* src;
  bf16* dst;
  const float* wt;
  float outscale;
  if (hh < 16) {
    src = QKV + (size_t)s * NQKV + hh * Dh;
    dst = Qn + ((size_t)hh * S + s) * Dh;
    wt = qw;
    outscale = ATTN_SCALE;
  } else {
    int kvh = hh - 16;
    src = QKV + (size_t)s * NQKV + 2048 + kvh * Dh;
    dst = Kn + ((size_t)kvh * S + s) * Dh;
    wt = kw;
    outscale = 1.0f;
  }

  float x0 = __bfloat162float(src[lane]);
  float x1 = __bfloat162float(src[lane + 64]);
  float ss = x0 * x0 + x1 * x1;
#pragma unroll
  for (int off = 1; off < 64; off <<= 1) ss += __shfl_xor(ss, off);
  float rms = rsqrtf(ss * (1.0f / 128.0f) + 1e-6f);
  float n0 = x0 * rms * wt[lane];
  float n1 = x1 * rms * wt[lane + 64];

  float inv_freq = exp2f((float)lane * -0.2076205059304601f);
  float ang = (float)s * inv_freq;
  float sn, cs;
  sincosf(ang, &sn, &cs);
  float o0 = (n0 * cs - n1 * sn) * outscale;
  float o1 = (n1 * cs + n0 * sn) * outscale;
  dst[lane] = __float2bfloat16(o0);
  dst[lane + 64] = __float2bfloat16(o1);
}

// ---------------- V transpose: Vt[kvh][d][s] = QKV[s][2560 + kvh*128 + d] ------
__global__ void v_transpose(const bf16* __restrict__ QKV, bf16* __restrict__ Vt) {
  __shared__ bf16 t[64][65];
  const int s0 = blockIdx.x * 64;
  const int c0 = blockIdx.y * 64;
  const int kvh = c0 >> 7, d0 = c0 & 127;
#pragma unroll 4
  for (int i = 0; i < 16; ++i) {
    int lin = i * 256 + threadIdx.x;
    int r = lin >> 6, c = lin & 63;
    t[r][c] = QKV[(size_t)(s0 + r) * NQKV + 2560 + c0 + c];
  }
  __syncthreads();
#pragma unroll 4
  for (int i = 0; i < 16; ++i) {
    int lin = i * 256 + threadIdx.x;
    int d = lin >> 6, s = lin & 63;
    Vt[((size_t)kvh * 128 + d0 + d) * S + s0 + s] = t[s][d];
  }
}

// ---------------- causal GQA flash attention (v2) ------------------------------
// grid (32, H): block = 4 waves x 16 q-rows = 64 q-rows, one head.
// K double-buffered in LDS (async global_load_lds, source-swizzled);
// V reg-staged -> swizzled LDS (single buffer); P via padded LDS.
__global__ __launch_bounds__(256, 2) void attn_fwd(const bf16* __restrict__ Qn,
                                                   const bf16* __restrict__ Kn,
                                                   const bf16* __restrict__ Vt,
                                                   bf16* __restrict__ AO) {
  __shared__ bf16 Ks[2][64 * 128];   // 2 x 16 KB, chunk-swizzled
  __shared__ bf16 Vs[128 * 64];      // 16 KB, [d][k] chunk-swizzled
  __shared__ bf16 Ps[4][16 * 80];    // per-wave P, stride 80 (16B-aligned rows)

  const int tid = threadIdx.x;
  const int lane = tid & 63;
  const int w = tid >> 6;
  const int lr = lane & 15, lq = lane >> 4;
  const int h = blockIdx.y, kvh = h >> 2;
  const int qi = (int)gridDim.x - 1 - blockIdx.x;   // big tiles dispatch first
  const int q0 = qi * 64;
  const int nt = q0 / 64 + 1;                       // 64-key tiles incl. diagonal

  const bf16* Qbase = Qn + ((size_t)h * S + q0 + w * 16) * Dh;
  const bf16* Kbase = Kn + (size_t)kvh * S * Dh;
  const bf16* Vbase = Vt + (size_t)kvh * Dh * S;
  bf16* Pw = &Ps[w][0];

  // Q fragments (A-operand), already scaled by 1/sqrt(Dh)
  short8 qf[4];
#pragma unroll
  for (int dd = 0; dd < 4; ++dd)
    qf[dd] = *reinterpret_cast<const short8*>(Qbase + (size_t)lr * Dh + dd * 32 + lq * 8);

  float mrow[4], lrow[4];
  f32x4 oacc[8] = {};
#pragma unroll
  for (int i = 0; i < 4; ++i) { mrow[i] = -INFINITY; lrow[i] = 0.0f; }

  float4 vreg[4];

  auto stageK = [&](int tile, int b) {
    const int kb = tile * 64;
#pragma unroll
    for (int i = 0; i < 4; ++i) {
      int chunk = i * 256 + tid;          // 16 chunks/row, 64 rows
      int r = chunk >> 4, c = chunk & 15;
      int cs = c ^ (r & 7);
      gload_lds16(Kbase + (size_t)(kb + r) * Dh + cs * 8,
                  (bf16*)Ks + b * 8192 + (i * 256 + w * 64) * 8);
    }
  };
  auto loadV = [&](int tile) {
    const int kb = tile * 64;
#pragma unroll
    for (int j = 0; j < 4; ++j) {
      int chunk = j * 256 + tid;          // 8 chunks/row, 128 rows
      int r = chunk >> 3, c = chunk & 7;
      vreg[j] = *reinterpret_cast<const float4*>(Vbase + (size_t)r * S + kb + c * 8);
    }
  };
  auto writeV = [&]() {
#pragma unroll
    for (int j = 0; j < 4; ++j) {
      int chunk = j * 256 + tid;
      int r = chunk >> 3, c = chunk & 7;
      int cs = c ^ (r & 7);
      *reinterpret_cast<float4*>((char*)Vs + r * 128 + cs * 16) = vreg[j];
    }
  };

  stageK(0, 0);
  loadV(0);
  __syncthreads();   // drain K(0) + V(0) regs
  writeV();
  int buf = 0;

  for (int t = 0; t < nt; ++t) {
    __syncthreads();  // publish Vs(t) and Ks[buf](t)
    if (t + 1 < nt) { stageK(t + 1, buf ^ 1); loadV(t + 1); }  // in flight over compute

    // ---- QK^T: 16 rows x 64 keys ----
    f32x4 sacc[4] = {};
#pragma unroll
    for (int jn = 0; jn < 4; ++jn) {
      int r = jn * 16 + lr;
      const char* kroww = (const char*)Ks + buf * 16384 + r * 256;
      int rx = r & 7;
#pragma unroll
      for (int dd = 0; dd < 4; ++dd) {
        int cg = (dd * 4 + lq) ^ rx;
        short8 bfr = *reinterpret_cast<const short8*>(kroww + cg * 16);
        sacc[jn] = MFMA16(qf[dd], bfr, sacc[jn]);
      }
    }

    // ---- online softmax (rows = w*16 + lq*4 + i) ----
    const bool lastt = (t == nt - 1);
    float pm[4] = {-INFINITY, -INFINITY, -INFINITY, -INFINITY};
#pragma unroll
    for (int jn = 0; jn < 4; ++jn)
#pragma unroll
      for (int i = 0; i < 4; ++i) {
        float v = sacc[jn][i];
        if (lastt && (jn * 16 + lr > w * 16 + lq * 4 + i)) v = -INFINITY;
        sacc[jn][i] = v;
        pm[i] = fmaxf(pm[i], v);
      }
#pragma unroll
    for (int i = 0; i < 4; ++i) {
      pm[i] = fmaxf(pm[i], __shfl_xor(pm[i], 1));
      pm[i] = fmaxf(pm[i], __shfl_xor(pm[i], 2));
      pm[i] = fmaxf(pm[i], __shfl_xor(pm[i], 4));
      pm[i] = fmaxf(pm[i], __shfl_xor(pm[i], 8));
    }
    float alpha[4], rs[4];
#pragma unroll
    for (int i = 0; i < 4; ++i) {
      float mnew = fmaxf(mrow[i], pm[i]);
      alpha[i] = __expf(mrow[i] - mnew);
      mrow[i] = mnew;
      rs[i] = 0.0f;
    }
#pragma unroll
    for (int jn = 0; jn < 4; ++jn)
#pragma unroll
      for (int i = 0; i < 4; ++i) {
        float p = __expf(sacc[jn][i] - mrow[i]);
        rs[i] += p;
        Pw[(lq * 4 + i) * 80 + jn * 16 + lr] = __float2bfloat16(p);
      }
#pragma unroll
    for (int i = 0; i < 4; ++i) {
      rs[i] += __shfl_xor(rs[i], 1);
      rs[i] += __shfl_xor(rs[i], 2);
      rs[i] += __shfl_xor(rs[i], 4);
      rs[i] += __shfl_xor(rs[i], 8);
      lrow[i] = lrow[i] * alpha[i] + rs[i];
    }
#pragma unroll
    for (int jd = 0; jd < 8; ++jd)
#pragma unroll
      for (int i = 0; i < 4; ++i) oacc[jd][i] *= alpha[i];

    __builtin_amdgcn_wave_barrier();

    // ---- O += P @ V ----
#pragma unroll
    for (int kk = 0; kk < 2; ++kk) {
      short8 pa = *reinterpret_cast<const short8*>(Pw + lr * 80 + kk * 32 + lq * 8);
#pragma unroll
      for (int jd = 0; jd < 8; ++jd) {
        int r = jd * 16 + lr;
        int cg = (kk * 4 + lq) ^ (r & 7);
        short8 vf = *reinterpret_cast<const short8*>((const char*)Vs + r * 128 + cg * 16);
        oacc[jd] = MFMA16(pa, vf, oacc[jd]);
      }
    }

    __syncthreads();  // everyone done with Vs + Ks[buf]; drains stage(t+1)
    if (t + 1 < nt) writeV();
    buf ^= 1;
  }

#pragma unroll
  for (int jd = 0; jd < 8; ++jd)
#pragma unroll
    for (int i = 0; i < 4; ++i) {
      float o = oacc[jd][i] / lrow[i];
      AO[(size_t)(q0 + w * 16 + lq * 4 + i) * E + h * Dh + jd * 16 + lr] = __float2bfloat16(o);
    }
}

// ------------------------------------------------------------------------------
extern "C" void kernel_launch(void* const* d_in, const int* in_sizes, int n_in,
                              void* d_out, int out_size, void* d_ws, size_t ws_size,
                              hipStream_t stream) {
  const float* x  = (const float*)d_in[0];
  const float* Wq = (const float*)d_in[2];
  const float* Wk = (const float*)d_in[3];
  const float* Wv = (const float*)d_in[4];
  const float* Wo = (const float*)d_in[5];
  const float* qw = (const float*)d_in[6];
  const float* kw = (const float*)d_in[7];

  char* ws = (char*)d_ws;
  bf16* xb   = (bf16*)(ws + (0ull << 20));    // [2048][2048]   8 MB
  bf16* Wcat = (bf16*)(ws + (8ull << 20));    // [3072][2048]  12 MB
  bf16* Wob  = (bf16*)(ws + (20ull << 20));   // [2048][2048]   8 MB
  bf16* QKV  = (bf16*)(ws + (28ull << 20));   // [2048][3072]  12 MB
  bf16* Qn   = (bf16*)(ws + (40ull << 20));   // [16][2048][128] 8 MB
  bf16* Kn   = (bf16*)(ws + (48ull << 20));   // [4][2048][128]  2 MB
  bf16* Vt   = (bf16*)(ws + (50ull << 20));   // [4][128][2048]  2 MB
  bf16* AO   = (bf16*)(ws + (52ull << 20));   // [2048][2048]    8 MB

  cvt_bf16<<<2048, 256, 0, stream>>>(x, xb, E * S);
  cvt_bf16<<<2048, 256, 0, stream>>>(Wq, Wcat, E * E);
  cvt_bf16<<<512, 256, 0, stream>>>(Wk, Wcat + 2048 * 2048, 512 * E);
  cvt_bf16<<<512, 256, 0, stream>>>(Wv, Wcat + 2560 * 2048, 512 * E);
  cvt_bf16<<<2048, 256, 0, stream>>>(Wo, Wob, E * E);

  gemm_nt<false><<<dim3(S / 128, NQKV / 128), 256, 0, stream>>>(xb, Wcat, QKV, S, NQKV, E);

  qk_norm_rope<<<(S * 20) / 4, 256, 0, stream>>>(QKV, qw, kw, Qn, Kn);
  v_transpose<<<dim3(S / 64, 512 / 64), 256, 0, stream>>>(QKV, Vt);

  attn_fwd<<<dim3(S / 64, H), 256, 0, stream>>>(Qn, Kn, Vt, AO);

  gemm_nt<true><<<dim3(S / 128, E / 128), 256, 0, stream>>>(AO, Wob, d_out, S, E, E);
}

// Round 4
// 212.975 us; speedup vs baseline: 1.4054x; 1.0912x over previous
//
#include <hip/hip_runtime.h>
#include <hip/hip_bf16.h>
#include <cstdint>
#include <cstddef>

using bf16 = __hip_bfloat16;
typedef __attribute__((ext_vector_type(8))) short short8;
typedef __attribute__((ext_vector_type(4))) float f32x4;

#define MFMA16(a, b, c) __builtin_amdgcn_mfma_f32_16x16x32_bf16((a), (b), (c), 0, 0, 0)

static constexpr int S = 2048;
static constexpr int E = 2048;
static constexpr int H = 16;
static constexpr int KVH = 4;
static constexpr int Dh = 128;
static constexpr int NQKV = 3072;        // 2048 q + 512 k + 512 v
static constexpr float ATTN_SCALE = 0.08838834764831845f; // 1/sqrt(128)

__device__ __forceinline__ short f2bs(float f) {
  __hip_bfloat16 h = __float2bfloat16(f);
  return *reinterpret_cast<short*>(&h);
}

__device__ __forceinline__ void gload_lds16(const void* g, void* l) {
  __builtin_amdgcn_global_load_lds(
      (const __attribute__((address_space(1))) unsigned int*)g,
      (__attribute__((address_space(3))) unsigned int*)l,
      16, 0, 0);
}

// ---------------- f32 -> bf16 convert (vectorized, 8 elems/thread) -------------
__global__ void cvt_bf16(const float* __restrict__ src, bf16* __restrict__ dst, int n) {
  int i = (blockIdx.x * 256 + threadIdx.x) * 8;
  if (i + 8 > n) return;
  const float4* s4 = reinterpret_cast<const float4*>(src + i);
  float4 a = s4[0];
  float4 b = s4[1];
  short8 o;
  o[0] = f2bs(a.x); o[1] = f2bs(a.y); o[2] = f2bs(a.z); o[3] = f2bs(a.w);
  o[4] = f2bs(b.x); o[5] = f2bs(b.y); o[6] = f2bs(b.z); o[7] = f2bs(b.w);
  *reinterpret_cast<short8*>(dst + i) = o;
}

// ---------------- GEMM: C[m][n] = sum_k A[m][k] * B[n][k]  (both row-major) ----
template <bool OUT_F32>
__global__ __launch_bounds__(256, 2) void gemm_nt(const bf16* __restrict__ A,
                                                  const bf16* __restrict__ B,
                                                  void* __restrict__ Cout,
                                                  int M, int N, int K) {
  __shared__ bf16 As[128 * 32];
  __shared__ bf16 Bs[128 * 32];
  const int tid = threadIdx.x;
  const int lane = tid & 63;
  const int wv = tid >> 6;
  const int lr = lane & 15, lq = lane >> 4;
  const int wm = (wv >> 1) * 64, wn = (wv & 1) * 64;
  const int bm = blockIdx.x * 128, bn = blockIdx.y * 128;

  f32x4 acc[4][4] = {};

  for (int k0 = 0; k0 < K; k0 += 32) {
    __syncthreads();
    for (int it = 0; it < 2; ++it) {
      int ci = it * 256 + tid;
      int row = ci >> 2, co = (ci & 3) * 8;
      gload_lds16(A + (size_t)(bm + row) * K + k0 + co, As + (it * 256 + wv * 64) * 8);
      gload_lds16(B + (size_t)(bn + row) * K + k0 + co, Bs + (it * 256 + wv * 64) * 8);
    }
    __syncthreads();

    short8 af[4], bfr[4];
#pragma unroll
    for (int im = 0; im < 4; ++im)
      af[im] = *reinterpret_cast<const short8*>(As + (wm + im * 16 + lr) * 32 + lq * 8);
#pragma unroll
    for (int jn = 0; jn < 4; ++jn)
      bfr[jn] = *reinterpret_cast<const short8*>(Bs + (wn + jn * 16 + lr) * 32 + lq * 8);
#pragma unroll
    for (int im = 0; im < 4; ++im)
#pragma unroll
      for (int jn = 0; jn < 4; ++jn)
        acc[im][jn] = MFMA16(af[im], bfr[jn], acc[im][jn]);
  }

#pragma unroll
  for (int im = 0; im < 4; ++im)
#pragma unroll
    for (int jn = 0; jn < 4; ++jn)
#pragma unroll
      for (int i = 0; i < 4; ++i) {
        int r = bm + wm + im * 16 + lq * 4 + i;
        int c = bn + wn + jn * 16 + lr;
        if (OUT_F32)
          reinterpret_cast<float*>(Cout)[(size_t)r * N + c] = acc[im][jn][i];
        else
          reinterpret_cast<bf16*>(Cout)[(size_t)r * N + c] = __float2bfloat16(acc[im][jn][i]);
      }
}

// ---------------- QK RMSNorm + RoPE (Q pre-scaled by 1/sqrt(Dh)) ---------------
__global__ void qk_norm_rope(const bf16* __restrict__ QKV,
                             const float* __restrict__ qw, const float* __restrict__ kw,
                             bf16* __restrict__ Qn, bf16* __restrict__ Kn) {
  const int lane = threadIdx.x & 63;
  const int w = threadIdx.x >> 6;
  const int row = blockIdx.x * 4 + w;
  const int s = row / 20;
  const int hh = row % 20;

  const bf16* src;
  bf16* dst;
  const float* wt;
  float outscale;
  if (hh < 16) {
    src = QKV + (size_t)s * NQKV + hh * Dh;
    dst = Qn + ((size_t)hh * S + s) * Dh;
    wt = qw;
    outscale = ATTN_SCALE;
  } else {
    int kvh = hh - 16;
    src = QKV + (size_t)s * NQKV + 2048 + kvh * Dh;
    dst = Kn + ((size_t)kvh * S + s) * Dh;
    wt = kw;
    outscale = 1.0f;
  }

  float x0 = __bfloat162float(src[lane]);
  float x1 = __bfloat162float(src[lane + 64]);
  float ss = x0 * x0 + x1 * x1;
#pragma unroll
  for (int off = 1; off < 64; off <<= 1) ss += __shfl_xor(ss, off);
  float rms = rsqrtf(ss * (1.0f / 128.0f) + 1e-6f);
  float n0 = x0 * rms * wt[lane];
  float n1 = x1 * rms * wt[lane + 64];

  float inv_freq = exp2f((float)lane * -0.2076205059304601f);
  float ang = (float)s * inv_freq;
  float sn, cs;
  sincosf(ang, &sn, &cs);
  float o0 = (n0 * cs - n1 * sn) * outscale;
  float o1 = (n1 * cs + n0 * sn) * outscale;
  dst[lane] = __float2bfloat16(o0);
  dst[lane + 64] = __float2bfloat16(o1);
}

// ---------------- V transpose: Vt[kvh][d][s] = QKV[s][2560 + kvh*128 + d] ------
__global__ void v_transpose(const bf16* __restrict__ QKV, bf16* __restrict__ Vt) {
  __shared__ bf16 t[64][65];
  const int s0 = blockIdx.x * 64;
  const int c0 = blockIdx.y * 64;
  const int kvh = c0 >> 7, d0 = c0 & 127;
#pragma unroll 4
  for (int i = 0; i < 16; ++i) {
    int lin = i * 256 + threadIdx.x;
    int r = lin >> 6, c = lin & 63;
    t[r][c] = QKV[(size_t)(s0 + r) * NQKV + 2560 + c0 + c];
  }
  __syncthreads();
#pragma unroll 4
  for (int i = 0; i < 16; ++i) {
    int lin = i * 256 + threadIdx.x;
    int d = lin >> 6, s = lin & 63;
    Vt[((size_t)kvh * 128 + d0 + d) * S + s0 + s] = t[s][d];
  }
}

// ---------------- chunk decode: u in [0,80) -> (qi, c, nc) ---------------------
__device__ __forceinline__ void chunk_decode(int u, int& qi, int& c, int& nc) {
  if (u < 8)       { qi = u;               c = 0;      nc = 1; }
  else if (u < 24) { int v = u - 8;  qi = 8  + (v >> 1); c = v & 1;  nc = 2; }
  else if (u < 48) { int v = u - 24; qi = 16 + v / 3;    c = v % 3;  nc = 3; }
  else             { int v = u - 48; qi = 24 + (v >> 2); c = v & 3;  nc = 4; }
}

// ---------------- causal GQA flash attention (v3: uniform KV-split chunks) -----
// 1280 blocks; block = (head, q-tile of 64 rows, kv-chunk of <=8 64-key tiles).
// 4 waves x 16 q-rows. K dbuf LDS (async, source-swizzled); V reg->swizzled LDS;
// P per-wave XOR-swizzled [16][64].
__global__ __launch_bounds__(256, 2) void attn_fwd(const bf16* __restrict__ Qn,
                                                   const bf16* __restrict__ Kn,
                                                   const bf16* __restrict__ Vt,
                                                   bf16* __restrict__ AO,
                                                   bf16* __restrict__ Opart,
                                                   float* __restrict__ ml) {
  __shared__ bf16 Ks[2][64 * 128];   // 2 x 16 KB, chunk-swizzled
  __shared__ bf16 Vs[128 * 64];      // 16 KB, [d][k] chunk-swizzled
  __shared__ bf16 Ps[4][16 * 64];    // per-wave P, XOR-swizzled, 2 KB each

  const int tid = threadIdx.x;
  const int lane = tid & 63;
  const int w = tid >> 6;
  const int lr = lane & 15, lq = lane >> 4;

  const int bx = blockIdx.x;
  const int h = bx / 80, u = bx % 80;
  int qi, cch, nc;
  chunk_decode(u, qi, cch, nc);
  const int kvh = h >> 2;
  const int q0 = qi * 64;
  const int t0 = cch * 8;
  const int t1 = min(t0 + 8, qi + 1);

  const bf16* Qbase = Qn + ((size_t)h * S + q0 + w * 16) * Dh;
  const bf16* Kbase = Kn + (size_t)kvh * S * Dh;
  const bf16* Vbase = Vt + (size_t)kvh * Dh * S;
  bf16* Pw = &Ps[w][0];

  short8 qf[4];
#pragma unroll
  for (int dd = 0; dd < 4; ++dd)
    qf[dd] = *reinterpret_cast<const short8*>(Qbase + (size_t)lr * Dh + dd * 32 + lq * 8);

  float mrow[4], lrow[4];
  f32x4 oacc[8] = {};
#pragma unroll
  for (int i = 0; i < 4; ++i) { mrow[i] = -INFINITY; lrow[i] = 0.0f; }

  float4 vreg[4];

  auto stageK = [&](int tile, int b) {
    const int kb = tile * 64;
#pragma unroll
    for (int i = 0; i < 4; ++i) {
      int chunk = i * 256 + tid;          // 16 chunks/row, 64 rows
      int r = chunk >> 4, c = chunk & 15;
      int cs = c ^ (r & 7);
      gload_lds16(Kbase + (size_t)(kb + r) * Dh + cs * 8,
                  (bf16*)Ks + b * 8192 + (i * 256 + w * 64) * 8);
    }
  };
  auto loadV = [&](int tile) {
    const int kb = tile * 64;
#pragma unroll
    for (int j = 0; j < 4; ++j) {
      int chunk = j * 256 + tid;          // 8 chunks/row, 128 rows
      int r = chunk >> 3, c = chunk & 7;
      vreg[j] = *reinterpret_cast<const float4*>(Vbase + (size_t)r * S + kb + c * 8);
    }
  };
  auto writeV = [&]() {
#pragma unroll
    for (int j = 0; j < 4; ++j) {
      int chunk = j * 256 + tid;
      int r = chunk >> 3, c = chunk & 7;
      int cs = c ^ (r & 7);
      *reinterpret_cast<float4*>((char*)Vs + r * 128 + cs * 16) = vreg[j];
    }
  };

  stageK(t0, 0);
  loadV(t0);
  __syncthreads();
  writeV();
  int buf = 0;

  for (int t = t0; t < t1; ++t) {
    __syncthreads();  // publish Vs(t) and Ks[buf](t)
    if (t + 1 < t1) { stageK(t + 1, buf ^ 1); loadV(t + 1); }

    // ---- QK^T: 16 rows x 64 keys ----
    f32x4 sacc[4] = {};
    __builtin_amdgcn_s_setprio(1);
#pragma unroll
    for (int jn = 0; jn < 4; ++jn) {
      int r = jn * 16 + lr;
      const char* kroww = (const char*)Ks + buf * 16384 + r * 256;
      int rx = r & 7;
#pragma unroll
      for (int dd = 0; dd < 4; ++dd) {
        int cg = (dd * 4 + lq) ^ rx;
        short8 bfr = *reinterpret_cast<const short8*>(kroww + cg * 16);
        sacc[jn] = MFMA16(qf[dd], bfr, sacc[jn]);
      }
    }
    __builtin_amdgcn_s_setprio(0);

    // ---- online softmax (rows = w*16 + lq*4 + i within the 64-row q-tile) ----
    const bool diag = (t == qi);
    float pm[4] = {-INFINITY, -INFINITY, -INFINITY, -INFINITY};
#pragma unroll
    for (int jn = 0; jn < 4; ++jn)
#pragma unroll
      for (int i = 0; i < 4; ++i) {
        float v = sacc[jn][i];
        // causal: key idx (jn*16+lr) vs query idx (w*16 + lq*4 + i)  [w*16 was
        // the round-3 bug — it was dropped]
        if (diag && (jn * 16 + lr > w * 16 + lq * 4 + i)) v = -INFINITY;
        sacc[jn][i] = v;
        pm[i] = fmaxf(pm[i], v);
      }
#pragma unroll
    for (int i = 0; i < 4; ++i) {
      pm[i] = fmaxf(pm[i], __shfl_xor(pm[i], 1));
      pm[i] = fmaxf(pm[i], __shfl_xor(pm[i], 2));
      pm[i] = fmaxf(pm[i], __shfl_xor(pm[i], 4));
      pm[i] = fmaxf(pm[i], __shfl_xor(pm[i], 8));
    }
    // defer-max: only rescale when the new tile max exceeds old max + 8
    float dm = fmaxf(fmaxf(pm[0] - mrow[0], pm[1] - mrow[1]),
                     fmaxf(pm[2] - mrow[2], pm[3] - mrow[3]));
    if (!__all(dm <= 8.0f)) {
#pragma unroll
      for (int i = 0; i < 4; ++i) {
        float mnew = fmaxf(mrow[i], pm[i]);
        float a = __expf(mrow[i] - mnew);
        mrow[i] = mnew;
        lrow[i] *= a;
#pragma unroll
        for (int jd = 0; jd < 8; ++jd) oacc[jd][i] *= a;
      }
    }
    float rs[4] = {0.0f, 0.0f, 0.0f, 0.0f};
#pragma unroll
    for (int jn = 0; jn < 4; ++jn)
#pragma unroll
      for (int i = 0; i < 4; ++i) {
        float p = __expf(sacc[jn][i] - mrow[i]);
        rs[i] += p;
        int row = lq * 4 + i;
        int col = jn * 16 + lr;
        int swz = ((col >> 3) ^ (row & 7));
        Pw[row * 64 + swz * 8 + (col & 7)] = __float2bfloat16(p);
      }
#pragma unroll
    for (int i = 0; i < 4; ++i) {
      rs[i] += __shfl_xor(rs[i], 1);
      rs[i] += __shfl_xor(rs[i], 2);
      rs[i] += __shfl_xor(rs[i], 4);
      rs[i] += __shfl_xor(rs[i], 8);
      lrow[i] += rs[i];
    }

    __builtin_amdgcn_wave_barrier();

    // ---- O += P @ V ----
    __builtin_amdgcn_s_setprio(1);
#pragma unroll
    for (int kk = 0; kk < 2; ++kk) {
      int swz = (kk * 4 + lq) ^ (lr & 7);
      short8 pa = *reinterpret_cast<const short8*>(Pw + lr * 64 + swz * 8);
#pragma unroll
      for (int jd = 0; jd < 8; ++jd) {
        int r = jd * 16 + lr;
        int cg = (kk * 4 + lq) ^ (r & 7);
        short8 vf = *reinterpret_cast<const short8*>((const char*)Vs + r * 128 + cg * 16);
        oacc[jd] = MFMA16(pa, vf, oacc[jd]);
      }
    }
    __builtin_amdgcn_s_setprio(0);

    __syncthreads();  // everyone done with Vs + Ks[buf]; drains stage(t+1)
    if (t + 1 < t1) writeV();
    buf ^= 1;
  }

  if (nc == 1) {
#pragma unroll
    for (int jd = 0; jd < 8; ++jd)
#pragma unroll
      for (int i = 0; i < 4; ++i) {
        float o = oacc[jd][i] / lrow[i];
        AO[(size_t)(q0 + w * 16 + lq * 4 + i) * E + h * Dh + jd * 16 + lr] = __float2bfloat16(o);
      }
  } else {
    const int pidx = h * 80 + u;
    bf16* Op = Opart + (size_t)pidx * 64 * 128;
#pragma unroll
    for (int jd = 0; jd < 8; ++jd)
#pragma unroll
      for (int i = 0; i < 4; ++i)
        Op[(w * 16 + lq * 4 + i) * 128 + jd * 16 + lr] = __float2bfloat16(oacc[jd][i]);
    if (lr == 0) {
#pragma unroll
      for (int i = 0; i < 4; ++i) {
        int row = w * 16 + lq * 4 + i;
        ml[(size_t)pidx * 128 + row * 2]     = mrow[i];
        ml[(size_t)pidx * 128 + row * 2 + 1] = lrow[i];
      }
    }
  }
}

// ---------------- combine partial chunks (qi >= 8) -----------------------------
__global__ __launch_bounds__(256) void attn_combine(const bf16* __restrict__ Opart,
                                                    const float* __restrict__ ml,
                                                    bf16* __restrict__ AO) {
  const int qi = 8 + blockIdx.x;
  const int h = blockIdx.y;
  const int nc = qi / 8 + 1;
  const int off = (qi < 16) ? 8 + (qi - 8) * 2
                : (qi < 24) ? 24 + (qi - 16) * 3
                            : 48 + (qi - 24) * 4;
  const int base = h * 80 + off;
  const int row = threadIdx.x >> 2;
  const int d0 = (threadIdx.x & 3) * 32;

  float mc[4], lc[4];
  float M = -INFINITY;
  for (int c = 0; c < nc; ++c) {
    mc[c] = ml[(size_t)(base + c) * 128 + row * 2];
    lc[c] = ml[(size_t)(base + c) * 128 + row * 2 + 1];
    M = fmaxf(M, mc[c]);
  }
  float L = 0.0f;
  float acc[32];
#pragma unroll
  for (int j = 0; j < 32; ++j) acc[j] = 0.0f;
  for (int c = 0; c < nc; ++c) {
    float wgt = __expf(mc[c] - M);
    L += wgt * lc[c];
    const short8* op = reinterpret_cast<const short8*>(
        Opart + (size_t)(base + c) * 8192 + row * 128 + d0);
#pragma unroll
    for (int j4 = 0; j4 < 4; ++j4) {
      short8 vv = op[j4];
#pragma unroll
      for (int e = 0; e < 8; ++e) {
        short sv = vv[e];
        acc[j4 * 8 + e] += wgt * __bfloat162float(*reinterpret_cast<bf16*>(&sv));
      }
    }
  }
  float inv = 1.0f / L;
  bf16* ao = AO + (size_t)(qi * 64 + row) * E + h * Dh + d0;
  short8 outv[4];
#pragma unroll
  for (int j4 = 0; j4 < 4; ++j4) {
#pragma unroll
    for (int e = 0; e < 8; ++e) outv[j4][e] = f2bs(acc[j4 * 8 + e] * inv);
    reinterpret_cast<short8*>(ao)[j4] = outv[j4];
  }
}

// ------------------------------------------------------------------------------
extern "C" void kernel_launch(void* const* d_in, const int* in_sizes, int n_in,
                              void* d_out, int out_size, void* d_ws, size_t ws_size,
                              hipStream_t stream) {
  const float* x  = (const float*)d_in[0];
  const float* Wq = (const float*)d_in[2];
  const float* Wk = (const float*)d_in[3];
  const float* Wv = (const float*)d_in[4];
  const float* Wo = (const float*)d_in[5];
  const float* qw = (const float*)d_in[6];
  const float* kw = (const float*)d_in[7];

  char* ws = (char*)d_ws;
  bf16* xb   = (bf16*)(ws + (0ull << 20));    // [2048][2048]   8 MB   (dead after GEMM1)
  bf16* Wcat = (bf16*)(ws + (8ull << 20));    // [3072][2048]  12 MB   (dead after GEMM1)
  bf16* Wob  = (bf16*)(ws + (20ull << 20));   // [2048][2048]   8 MB
  bf16* QKV  = (bf16*)(ws + (28ull << 20));   // [2048][3072]  12 MB   (dead after norm/transpose)
  bf16* Qn   = (bf16*)(ws + (40ull << 20));   // [16][2048][128] 8 MB
  bf16* Kn   = (bf16*)(ws + (48ull << 20));   // [4][2048][128]  2 MB
  bf16* Vt   = (bf16*)(ws + (50ull << 20));   // [4][128][2048]  2 MB
  bf16* AO   = (bf16*)(ws + (52ull << 20));   // [2048][2048]    8 MB
  bf16* Opart = (bf16*)(ws + (0ull << 20));   // 1280 x [64][128] = 20 MB, reuses xb+Wcat
  float* ml   = (float*)(ws + (28ull << 20)); // 1280 x 128 f32 = 640 KB, reuses QKV

  cvt_bf16<<<2048, 256, 0, stream>>>(x, xb, E * S);
  cvt_bf16<<<2048, 256, 0, stream>>>(Wq, Wcat, E * E);
  cvt_bf16<<<512, 256, 0, stream>>>(Wk, Wcat + 2048 * 2048, 512 * E);
  cvt_bf16<<<512, 256, 0, stream>>>(Wv, Wcat + 2560 * 2048, 512 * E);
  cvt_bf16<<<2048, 256, 0, stream>>>(Wo, Wob, E * E);

  gemm_nt<false><<<dim3(S / 128, NQKV / 128), 256, 0, stream>>>(xb, Wcat, QKV, S, NQKV, E);

  qk_norm_rope<<<(S * 20) / 4, 256, 0, stream>>>(QKV, qw, kw, Qn, Kn);
  v_transpose<<<dim3(S / 64, 512 / 64), 256, 0, stream>>>(QKV, Vt);

  attn_fwd<<<16 * 80, 256, 0, stream>>>(Qn, Kn, Vt, AO, Opart, ml);
  attn_combine<<<dim3(24, 16), 256, 0, stream>>>(Opart, ml, AO);

  gemm_nt<true><<<dim3(S / 128, E / 128), 256, 0, stream>>>(AO, Wob, d_out, S, E, E);
}